// Round 1
// baseline (919.768 us; speedup 1.0000x reference)
//
#include <hip/hip_runtime.h>
#include <math.h>

#define N 524288
#define K 65536
#define IN_C 128
#define OUT_C 256

// ---- workspace layout (byte offsets) ----
#define WS_INV     0                               // int[N]      2 MB
#define WS_CNT     (2*1024*1024)                   // int[2*K]    512 KB
#define WS_BASE    (WS_CNT + 512*1024)             // int[2*K]    512 KB
#define WS_BINBUF  (WS_BASE + 512*1024)            // int[2*K*8]  4 MB
#define WS_BS      (WS_BINBUF + 4*1024*1024)       // float[256*256]
#define WS_BSQ     (WS_BS + 256*1024)              // float[256*256]
#define WS_MV      (WS_BSQ + 256*1024)             // float[512]
#define WS_FLAG    (WS_MV + 2048)                  // int[1]

// ---- d_out layout (float element offsets, return order) ----
#define O_FEAT  0                    // (K,256)
#define O_CMEAN (K*256)              // (K,3)
#define O_PCODE (O_CMEAN + K*3)      // (3,K)
#define O_PORD  (O_PCODE + 3*K)      // (3,K)
#define O_PINV  (O_PORD + 3*K)       // (3,K)
#define O_PGRID (O_PINV + 3*K)       // (K,3)

__device__ __forceinline__ int imin(int a, int b) { return a < b ? a : b; }
__device__ __forceinline__ int imax(int a, int b) { return a > b ? a : b; }

// detect whether serialized_code is int32 (flag=1) or int64 (flag=0).
// int64 values < 2^31 -> all odd 32-bit words are 0; an int32 permutation
// cannot have 128 zeros in the first 256 slots.
__global__ void detect_kernel(const unsigned int* __restrict__ sc, int* __restrict__ flag) {
    if (threadIdx.x == 0) {
        unsigned int f = 0;
        for (int j = 1; j < 256; j += 2) f |= sc[j];
        *flag = (f != 0u) ? 1 : 0;
    }
}

__global__ void build_inv_kernel(const void* __restrict__ sc, const int* __restrict__ flag,
                                 int* __restrict__ inv) {
    const int i = blockIdx.x * 256 + threadIdx.x;
    long long v;
    if (*flag) v = (long long)((const int*)sc)[i];
    else       v = ((const long long*)sc)[i];
    inv[(int)v] = i;
}

#define SORT8(m, CSW) \
    CSW(m,0,1) CSW(m,2,3) CSW(m,4,5) CSW(m,6,7) \
    CSW(m,0,2) CSW(m,1,3) CSW(m,4,6) CSW(m,5,7) \
    CSW(m,1,2) CSW(m,5,6) \
    CSW(m,0,4) CSW(m,1,5) CSW(m,2,6) CSW(m,3,7) \
    CSW(m,2,4) CSW(m,3,5) \
    CSW(m,1,2) CSW(m,3,4) CSW(m,5,6)
#define CSWI(m,a,b) { int lo = imin(m[a], m[b]); int hi = imax(m[a], m[b]); m[a] = lo; m[b] = hi; }

__global__ void cluster_prep_kernel(const int* __restrict__ inv, const void* __restrict__ sc,
                                    const int* __restrict__ flag,
                                    const float* __restrict__ coord,
                                    const int* __restrict__ grid_coord,
                                    float* __restrict__ dout,
                                    int* __restrict__ cnt, int* __restrict__ binbuf) {
    const int c = blockIdx.x * 256 + threadIdx.x;  // cluster id
    int m[8];
#pragma unroll
    for (int j = 0; j < 8; ++j) m[j] = inv[c * 8 + j];
    SORT8(m, CSWI)                  // ascending original index (matches stable argsort order)
    const int head = m[0];

    float sx = 0.f, sy = 0.f, sz = 0.f;
#pragma unroll
    for (int j = 0; j < 8; ++j) {
        const float* cp = coord + (size_t)m[j] * 3;
        sx += cp[0]; sy += cp[1]; sz += cp[2];
    }
    dout[O_CMEAN + c * 3 + 0] = sx * 0.125f;
    dout[O_CMEAN + c * 3 + 1] = sy * 0.125f;
    dout[O_CMEAN + c * 3 + 2] = sz * 0.125f;

#pragma unroll
    for (int d = 0; d < 3; ++d)
        dout[O_PGRID + c * 3 + d] = (float)(grid_coord[head * 3 + d] >> 1);

    const int is32 = *flag;
#pragma unroll
    for (int r = 0; r < 3; ++r) {
        long long v = is32 ? (long long)((const int*)sc)[(size_t)r * N + head]
                           : ((const long long*)sc)[(size_t)r * N + head];
        const int pc = (int)(v >> 3);
        dout[O_PCODE + r * K + c] = (float)pc;
        if (r >= 1) {
            const int idx = (r - 1) * K + pc;
            const int slot = atomicAdd(&cnt[idx], 1);
            binbuf[idx * 8 + slot] = c;
        }
    }
    // row 0 of pooled_order / pooled_inverse is the identity
    dout[O_PORD + c] = (float)c;
    dout[O_PINV + c] = (float)c;
}

__global__ void scan_kernel(const int* __restrict__ cnt, int* __restrict__ base) {
    __shared__ int lds[1024];
    const int r = blockIdx.x, t = threadIdx.x;
    const int* c = cnt + r * K;
    int* b = base + r * K;
    const int off = t * 64;
    int s = 0;
    for (int j = 0; j < 64; ++j) s += c[off + j];
    lds[t] = s;
    __syncthreads();
    for (int d = 1; d < 1024; d <<= 1) {
        int add = (t >= d) ? lds[t - d] : 0;
        __syncthreads();
        lds[t] += add;
        __syncthreads();
    }
    int run = (t == 0) ? 0 : lds[t - 1];
    for (int j = 0; j < 64; ++j) { b[off + j] = run; run += c[off + j]; }
}

__global__ void scatter_kernel(const int* __restrict__ cnt, const int* __restrict__ base,
                               const int* __restrict__ binbuf, float* __restrict__ dout) {
    const int gid = blockIdx.x * 256 + threadIdx.x;  // [0, 2K): (row-1)*K + keybin
    const int n = cnt[gid];
    if (n == 0) return;
    int v[8];
#pragma unroll
    for (int j = 0; j < 8; ++j) v[j] = (j < n) ? binbuf[gid * 8 + j] : 0x7fffffff;
    SORT8(v, CSWI)                  // ascending cluster id -> stable within equal keys
    const int row = 1 + (gid >> 16);
    const int bp = base[gid];
#pragma unroll
    for (int j = 0; j < 8; ++j) {
        if (j < n) {
            const int cc = v[j];
            dout[O_PORD + row * K + bp + j] = (float)cc;
            dout[O_PINV + row * K + cc] = (float)(bp + j);
        }
    }
}

// Fused (feat @ W.T + b) -> segment-max over the 8 members of each cluster.
// Block: 8 clusters (64 feat rows) x 256 channels. Full feat tile + 32-wide W
// k-chunk in LDS (70656 B -> 2 blocks/CU). Thread: 8 members x 8 channels tile.
__global__ __launch_bounds__(256, 2) void gemm_max_kernel(
        const float* __restrict__ feat, const float* __restrict__ W,
        const float* __restrict__ bias, const int* __restrict__ inv,
        float* __restrict__ out) {
    __shared__ float sF[64 * 132];   // 64 rows, padded stride 132 (16B-aligned, breaks write conflicts)
    __shared__ float sW[256 * 36];   // 256 ch x 32-k chunk, padded stride 36
    const int t = threadIdx.x;
    const int blk = blockIdx.x;

    // stage feat tile: thread -> row t>>2, 32-float segment t&3 (coalesced per 4 lanes)
    {
        const int r = t >> 2, seg = t & 3;
        const int mi = inv[blk * 64 + r];
        const float4* gf = (const float4*)(feat + (size_t)mi * IN_C + seg * 32);
        float4* lf = (float4*)(sF + r * 132 + seg * 32);
#pragma unroll
        for (int u = 0; u < 8; ++u) lf[u] = gf[u];
    }

    float acc[8][8];
#pragma unroll
    for (int m = 0; m < 8; ++m)
#pragma unroll
        for (int i = 0; i < 8; ++i) acc[m][i] = 0.f;

    const int cc = t >> 5;   // cluster within block
    const int og = t & 31;   // channel group: channels og + 32*i

    for (int kc = 0; kc < 4; ++kc) {
        // stage W chunk cols [kc*32, kc*32+32): coalesced reads, conflict-free writes
#pragma unroll
        for (int p = 0; p < 32; ++p) {
            const int o = p * 8 + (t >> 5);
            const int kk = t & 31;
            sW[o * 36 + kk] = W[o * IN_C + kc * 32 + kk];
        }
        __syncthreads();
#pragma unroll
        for (int k4 = 0; k4 < 8; ++k4) {
            float4 w[8];
#pragma unroll
            for (int i = 0; i < 8; ++i)
                w[i] = *(const float4*)(sW + (og + 32 * i) * 36 + k4 * 4);
#pragma unroll
            for (int m = 0; m < 8; ++m) {
                const float4 f = *(const float4*)(sF + (cc * 8 + m) * 132 + kc * 32 + k4 * 4);
#pragma unroll
                for (int i = 0; i < 8; ++i) {
                    acc[m][i] = fmaf(f.x, w[i].x, acc[m][i]);
                    acc[m][i] = fmaf(f.y, w[i].y, acc[m][i]);
                    acc[m][i] = fmaf(f.z, w[i].z, acc[m][i]);
                    acc[m][i] = fmaf(f.w, w[i].w, acc[m][i]);
                }
            }
        }
        __syncthreads();
    }

    const int cg = blk * 8 + cc;
#pragma unroll
    for (int i = 0; i < 8; ++i) {
        float v = acc[0][i];
#pragma unroll
        for (int m = 1; m < 8; ++m) v = fmaxf(v, acc[m][i]);
        out[(size_t)cg * OUT_C + og + 32 * i] = v + bias[og + 32 * i];  // bias commutes with max
    }
}

__global__ void colreduce_kernel(const float* __restrict__ fm,
                                 float* __restrict__ bs, float* __restrict__ bsq) {
    const int b = blockIdx.x, t = threadIdx.x;   // block = 256-row stripe, thread = channel
    float s = 0.f, sq = 0.f;
    for (int r = 0; r < 256; ++r) {
        float v = fm[(size_t)(b * 256 + r) * 256 + t];
        s += v; sq += v * v;
    }
    bs[b * 256 + t] = s;
    bsq[b * 256 + t] = sq;
}

__global__ void finalize_kernel(const float* __restrict__ bs, const float* __restrict__ bsq,
                                float* __restrict__ mv) {
    const int o = threadIdx.x;
    float s = 0.f, sq = 0.f;
    for (int j = 0; j < 256; ++j) { s += bs[j * 256 + o]; sq += bsq[j * 256 + o]; }
    const float mean = s * (1.f / 65536.f);
    const float var = sq * (1.f / 65536.f) - mean * mean;
    mv[o] = mean;
    mv[256 + o] = rsqrtf(var + 0.001f);
}

__global__ void bn_gelu_kernel(float* __restrict__ out, const float* __restrict__ mv,
                               const float* __restrict__ gamma, const float* __restrict__ beta) {
    const int gid = blockIdx.x * 256 + threadIdx.x;
    float4 v = ((float4*)out)[gid];
    const int o0 = (gid * 4) & 255;
    float r[4] = {v.x, v.y, v.z, v.w};
#pragma unroll
    for (int j = 0; j < 4; ++j) {
        const int o = o0 + j;
        float x = (r[j] - mv[o]) * mv[256 + o] * gamma[o] + beta[o];
        r[j] = x * 0.5f * (1.f + erff(x * 0.70710678118654752f));
    }
    ((float4*)out)[gid] = make_float4(r[0], r[1], r[2], r[3]);
}

extern "C" void kernel_launch(void* const* d_in, const int* in_sizes, int n_in,
                              void* d_out, int out_size, void* d_ws, size_t ws_size,
                              hipStream_t stream) {
    const float* feat  = (const float*)d_in[0];
    const float* coord = (const float*)d_in[1];
    const float* W     = (const float*)d_in[2];
    const float* bias  = (const float*)d_in[3];
    const float* gamma = (const float*)d_in[4];
    const float* beta  = (const float*)d_in[5];
    const void*  sc    = d_in[6];
    const int*   gridc = (const int*)d_in[7];
    float* out = (float*)d_out;
    char* ws = (char*)d_ws;

    int*   inv    = (int*)(ws + WS_INV);
    int*   cnt    = (int*)(ws + WS_CNT);
    int*   base   = (int*)(ws + WS_BASE);
    int*   binbuf = (int*)(ws + WS_BINBUF);
    float* bs     = (float*)(ws + WS_BS);
    float* bsq    = (float*)(ws + WS_BSQ);
    float* mv     = (float*)(ws + WS_MV);
    int*   flag   = (int*)(ws + WS_FLAG);

    hipMemsetAsync(cnt, 0, 2 * K * sizeof(int), stream);
    detect_kernel<<<1, 64, 0, stream>>>((const unsigned int*)sc, flag);
    build_inv_kernel<<<N / 256, 256, 0, stream>>>(sc, flag, inv);
    cluster_prep_kernel<<<K / 256, 256, 0, stream>>>(inv, sc, flag, coord, gridc, out, cnt, binbuf);
    scan_kernel<<<2, 1024, 0, stream>>>(cnt, base);
    scatter_kernel<<<(2 * K) / 256, 256, 0, stream>>>(cnt, base, binbuf, out);
    gemm_max_kernel<<<K / 8, 256, 0, stream>>>(feat, W, bias, inv, out);
    colreduce_kernel<<<256, 256, 0, stream>>>(out, bs, bsq);
    finalize_kernel<<<1, 256, 0, stream>>>(bs, bsq, mv);
    bn_gelu_kernel<<<(K * 256) / (256 * 4), 256, 0, stream>>>(out, mv, gamma, beta);
}

// Round 2
// 610.613 us; speedup vs baseline: 1.5063x; 1.5063x over previous
//
#include <hip/hip_runtime.h>
#include <math.h>

#define N 524288
#define K 65536
#define IN_C 128
#define OUT_C 256

typedef __attribute__((ext_vector_type(8))) short short8;
typedef __attribute__((ext_vector_type(4))) float f32x4;

// ---- workspace layout (byte offsets) ----
#define WS_INV     0                               // int[N]      2 MB
#define WS_CNT     (2*1024*1024)                   // int[2*K]    512 KB
#define WS_BASE    (WS_CNT + 512*1024)             // int[2*K]    512 KB
#define WS_BINBUF  (WS_BASE + 512*1024)            // int[2*K*8]  4 MB
#define WS_BS      (WS_BINBUF + 4*1024*1024)       // float[256*256]
#define WS_BSQ     (WS_BS + 256*1024)              // float[256*256]
#define WS_MV      (WS_BSQ + 256*1024)             // float[512]
#define WS_FLAG    (WS_MV + 2048)                  // int[1]

// ---- d_out layout (float element offsets, return order) ----
#define O_FEAT  0                    // (K,256)
#define O_CMEAN (K*256)              // (K,3)
#define O_PCODE (O_CMEAN + K*3)      // (3,K)
#define O_PORD  (O_PCODE + 3*K)      // (3,K)
#define O_PINV  (O_PORD + 3*K)       // (3,K)
#define O_PGRID (O_PINV + 3*K)       // (K,3)

__device__ __forceinline__ int imin(int a, int b) { return a < b ? a : b; }
__device__ __forceinline__ int imax(int a, int b) { return a > b ? a : b; }

__device__ __forceinline__ unsigned short bf16_rne(float x) {
    unsigned int u = __float_as_uint(x);
    unsigned int r = u + 0x7fffu + ((u >> 16) & 1u);
    return (unsigned short)(r >> 16);
}

// detect whether serialized_code is int32 (flag=1) or int64 (flag=0).
__global__ void detect_kernel(const unsigned int* __restrict__ sc, int* __restrict__ flag) {
    if (threadIdx.x == 0) {
        unsigned int f = 0;
        for (int j = 1; j < 256; j += 2) f |= sc[j];
        *flag = (f != 0u) ? 1 : 0;
    }
}

__global__ void build_inv_kernel(const void* __restrict__ sc, const int* __restrict__ flag,
                                 int* __restrict__ inv) {
    const int i = blockIdx.x * 256 + threadIdx.x;
    long long v;
    if (*flag) v = (long long)((const int*)sc)[i];
    else       v = ((const long long*)sc)[i];
    inv[(int)v] = i;
}

#define SORT8(m, CSW) \
    CSW(m,0,1) CSW(m,2,3) CSW(m,4,5) CSW(m,6,7) \
    CSW(m,0,2) CSW(m,1,3) CSW(m,4,6) CSW(m,5,7) \
    CSW(m,1,2) CSW(m,5,6) \
    CSW(m,0,4) CSW(m,1,5) CSW(m,2,6) CSW(m,3,7) \
    CSW(m,2,4) CSW(m,3,5) \
    CSW(m,1,2) CSW(m,3,4) CSW(m,5,6)
#define CSWI(m,a,b) { int lo = imin(m[a], m[b]); int hi = imax(m[a], m[b]); m[a] = lo; m[b] = hi; }

__global__ void cluster_prep_kernel(const int* __restrict__ inv, const void* __restrict__ sc,
                                    const int* __restrict__ flag,
                                    const float* __restrict__ coord,
                                    const int* __restrict__ grid_coord,
                                    float* __restrict__ dout,
                                    int* __restrict__ cnt, int* __restrict__ binbuf) {
    const int c = blockIdx.x * 256 + threadIdx.x;  // cluster id
    int m[8];
#pragma unroll
    for (int j = 0; j < 8; ++j) m[j] = inv[c * 8 + j];
    SORT8(m, CSWI)                  // ascending original index (stable argsort order)
    const int head = m[0];

    float sx = 0.f, sy = 0.f, sz = 0.f;
#pragma unroll
    for (int j = 0; j < 8; ++j) {
        const float* cp = coord + (size_t)m[j] * 3;
        sx += cp[0]; sy += cp[1]; sz += cp[2];
    }
    dout[O_CMEAN + c * 3 + 0] = sx * 0.125f;
    dout[O_CMEAN + c * 3 + 1] = sy * 0.125f;
    dout[O_CMEAN + c * 3 + 2] = sz * 0.125f;

#pragma unroll
    for (int d = 0; d < 3; ++d)
        dout[O_PGRID + c * 3 + d] = (float)(grid_coord[head * 3 + d] >> 1);

    const int is32 = *flag;
#pragma unroll
    for (int r = 0; r < 3; ++r) {
        long long v = is32 ? (long long)((const int*)sc)[(size_t)r * N + head]
                           : ((const long long*)sc)[(size_t)r * N + head];
        const int pc = (int)(v >> 3);
        dout[O_PCODE + r * K + c] = (float)pc;
        if (r >= 1) {
            const int idx = (r - 1) * K + pc;
            const int slot = atomicAdd(&cnt[idx], 1);
            binbuf[idx * 8 + slot] = c;
        }
    }
    dout[O_PORD + c] = (float)c;   // row 0 is identity
    dout[O_PINV + c] = (float)c;
}

__global__ void scan_kernel(const int* __restrict__ cnt, int* __restrict__ base) {
    __shared__ int lds[1024];
    const int r = blockIdx.x, t = threadIdx.x;
    const int* c = cnt + r * K;
    int* b = base + r * K;
    const int off = t * 64;
    int s = 0;
    for (int j = 0; j < 64; ++j) s += c[off + j];
    lds[t] = s;
    __syncthreads();
    for (int d = 1; d < 1024; d <<= 1) {
        int add = (t >= d) ? lds[t - d] : 0;
        __syncthreads();
        lds[t] += add;
        __syncthreads();
    }
    int run = (t == 0) ? 0 : lds[t - 1];
    for (int j = 0; j < 64; ++j) { b[off + j] = run; run += c[off + j]; }
}

__global__ void scatter_kernel(const int* __restrict__ cnt, const int* __restrict__ base,
                               const int* __restrict__ binbuf, float* __restrict__ dout) {
    const int gid = blockIdx.x * 256 + threadIdx.x;  // [0, 2K)
    const int n = cnt[gid];
    if (n == 0) return;
    int v[8];
#pragma unroll
    for (int j = 0; j < 8; ++j) v[j] = (j < n) ? binbuf[gid * 8 + j] : 0x7fffffff;
    SORT8(v, CSWI)                  // ascending cluster id -> stable within equal keys
    const int row = 1 + (gid >> 16);
    const int bp = base[gid];
#pragma unroll
    for (int j = 0; j < 8; ++j) {
        if (j < n) {
            const int cc = v[j];
            dout[O_PORD + row * K + bp + j] = (float)cc;
            dout[O_PINV + row * K + cc] = (float)(bp + j);
        }
    }
}

// Split-bf16 MFMA GEMM fused with 8-way segment-max.
// Block: 512 threads (8 waves), 256 gathered rows (32 clusters) x 256 cols.
// W staged once per block in LDS as bf16 hi/lo [256][128], XOR-chunk-swizzled
// (chunk ^= col&7 -> 16-lane column-slice ds_read_b128 is 2-way = free).
// A gathered global->VGPR (f32), split to bf16 in-register, prefetched 1 k-step.
// Wave: 32 rows (2 row-tiles of 16) x 256 cols; acc = 2x16 f32x4 = 128 VGPR.
__global__ __launch_bounds__(512, 1) void gemm_max_kernel(
        const float* __restrict__ feat, const float* __restrict__ W,
        const float* __restrict__ bias, const int* __restrict__ inv,
        float* __restrict__ out) {
    __shared__ short sWh[256 * 128];   // 64 KB
    __shared__ short sWl[256 * 128];   // 64 KB
    const int t = threadIdx.x;
    const int blk = blockIdx.x;

    // ---- stage W (f32 -> bf16 hi/lo), swizzled ----
    {
#pragma unroll
        for (int i = 0; i < 8; ++i) {
            const int chunk = i * 512 + t;       // 4096 chunks of 8 floats
            const int c = chunk >> 4;            // out channel
            const int kk = chunk & 15;           // 8-float chunk within row
            const float4* wp = (const float4*)(W + c * IN_C + kk * 8);
            const float4 f0 = wp[0], f1 = wp[1];
            short8 hv, lv;
            float xs[8] = {f0.x, f0.y, f0.z, f0.w, f1.x, f1.y, f1.z, f1.w};
#pragma unroll
            for (int j = 0; j < 8; ++j) {
                const unsigned short h = bf16_rne(xs[j]);
                hv[j] = (short)h;
                const float hf = __uint_as_float((unsigned int)h << 16);
                lv[j] = (short)bf16_rne(xs[j] - hf);
            }
            const int swz = kk ^ (c & 7);
            *(short8*)&sWh[(c << 7) + (swz << 3)] = hv;
            *(short8*)&sWl[(c << 7) + (swz << 3)] = lv;
        }
    }

    const int wid = t >> 6;
    const int l = t & 63;
    const int lr = l & 15;            // row within 16-tile / col within col-tile
    const int lkg = l >> 4;           // k-group (0..3)

    // gathered row pointers for the wave's 2 row-tiles
    const float* ap[2];
#pragma unroll
    for (int rt = 0; rt < 2; ++rt) {
        const int g = blk * 256 + wid * 32 + rt * 16 + lr;
        ap[rt] = feat + (size_t)inv[g] * IN_C + (lkg << 3);
    }

    f32x4 acc[2][16];
#pragma unroll
    for (int rt = 0; rt < 2; ++rt)
#pragma unroll
        for (int ct = 0; ct < 16; ++ct) acc[rt][ct] = (f32x4)0.f;

    // prefetch k-step 0
    float4 ra[2][2];
#pragma unroll
    for (int rt = 0; rt < 2; ++rt) {
        ra[rt][0] = *(const float4*)(ap[rt]);
        ra[rt][1] = *(const float4*)(ap[rt] + 4);
    }

    __syncthreads();

#pragma unroll
    for (int ks = 0; ks < 4; ++ks) {
        float4 cur[2][2];
#pragma unroll
        for (int rt = 0; rt < 2; ++rt) { cur[rt][0] = ra[rt][0]; cur[rt][1] = ra[rt][1]; }
        if (ks < 3) {
#pragma unroll
            for (int rt = 0; rt < 2; ++rt) {
                ra[rt][0] = *(const float4*)(ap[rt] + (ks + 1) * 32);
                ra[rt][1] = *(const float4*)(ap[rt] + (ks + 1) * 32 + 4);
            }
        }
        // split to bf16 hi/lo fragments
        short8 ah[2], al[2];
#pragma unroll
        for (int rt = 0; rt < 2; ++rt) {
            float xs[8] = {cur[rt][0].x, cur[rt][0].y, cur[rt][0].z, cur[rt][0].w,
                           cur[rt][1].x, cur[rt][1].y, cur[rt][1].z, cur[rt][1].w};
#pragma unroll
            for (int j = 0; j < 8; ++j) {
                const unsigned short h = bf16_rne(xs[j]);
                ah[rt][j] = (short)h;
                const float hf = __uint_as_float((unsigned int)h << 16);
                al[rt][j] = (short)bf16_rne(xs[j] - hf);
            }
        }
#pragma unroll
        for (int ct = 0; ct < 16; ++ct) {
            const int cc = ct * 16 + lr;                      // B column
            const int chunk = ((ks << 2) + lkg) ^ (cc & 7);   // swizzled 8-elem chunk
            const int lbase = (cc << 7) + (chunk << 3);
            const short8 bh = *(const short8*)&sWh[lbase];
            const short8 bl = *(const short8*)&sWl[lbase];
#pragma unroll
            for (int rt = 0; rt < 2; ++rt) {
                acc[rt][ct] = __builtin_amdgcn_mfma_f32_16x16x32_bf16(ah[rt], bh, acc[rt][ct], 0, 0, 0);
                acc[rt][ct] = __builtin_amdgcn_mfma_f32_16x16x32_bf16(al[rt], bh, acc[rt][ct], 0, 0, 0);
                acc[rt][ct] = __builtin_amdgcn_mfma_f32_16x16x32_bf16(ah[rt], bl, acc[rt][ct], 0, 0, 0);
            }
        }
    }

    // ---- epilogue: 8-way segment-max + bias ----
    // C/D layout: col = lane&15, row = (lane>>4)*4 + reg  [m89]
    const int cb = blk * 32 + wid * 4;
#pragma unroll
    for (int rt = 0; rt < 2; ++rt) {
#pragma unroll
        for (int ct = 0; ct < 16; ++ct) {
            const f32x4 a = acc[rt][ct];
            float m4 = fmaxf(fmaxf(a[0], a[1]), fmaxf(a[2], a[3]));
            const float pm = __shfl_xor(m4, 16);
            const float m8 = fmaxf(m4, pm);
            const int col = ct * 16 + lr;
            if (l < 16)
                out[O_FEAT + (size_t)(cb + rt * 2 + 0) * OUT_C + col] = m8 + bias[col];
            else if (l >= 32 && l < 48)
                out[O_FEAT + (size_t)(cb + rt * 2 + 1) * OUT_C + col] = m8 + bias[col];
        }
    }
}

__global__ void colreduce_kernel(const float* __restrict__ fm,
                                 float* __restrict__ bs, float* __restrict__ bsq) {
    const int b = blockIdx.x, t = threadIdx.x;
    float s = 0.f, sq = 0.f;
    for (int r = 0; r < 256; ++r) {
        float v = fm[(size_t)(b * 256 + r) * 256 + t];
        s += v; sq += v * v;
    }
    bs[b * 256 + t] = s;
    bsq[b * 256 + t] = sq;
}

__global__ void finalize_kernel(const float* __restrict__ bs, const float* __restrict__ bsq,
                                float* __restrict__ mv) {
    const int o = threadIdx.x;
    float s = 0.f, sq = 0.f;
    for (int j = 0; j < 256; ++j) { s += bs[j * 256 + o]; sq += bsq[j * 256 + o]; }
    const float mean = s * (1.f / 65536.f);
    const float var = sq * (1.f / 65536.f) - mean * mean;
    mv[o] = mean;
    mv[256 + o] = rsqrtf(var + 0.001f);
}

__global__ void bn_gelu_kernel(float* __restrict__ out, const float* __restrict__ mv,
                               const float* __restrict__ gamma, const float* __restrict__ beta) {
    const int gid = blockIdx.x * 256 + threadIdx.x;
    float4 v = ((float4*)out)[gid];
    const int o0 = (gid * 4) & 255;
    float r[4] = {v.x, v.y, v.z, v.w};
#pragma unroll
    for (int j = 0; j < 4; ++j) {
        const int o = o0 + j;
        float x = (r[j] - mv[o]) * mv[256 + o] * gamma[o] + beta[o];
        r[j] = x * 0.5f * (1.f + erff(x * 0.70710678118654752f));
    }
    ((float4*)out)[gid] = make_float4(r[0], r[1], r[2], r[3]);
}

extern "C" void kernel_launch(void* const* d_in, const int* in_sizes, int n_in,
                              void* d_out, int out_size, void* d_ws, size_t ws_size,
                              hipStream_t stream) {
    const float* feat  = (const float*)d_in[0];
    const float* coord = (const float*)d_in[1];
    const float* W     = (const float*)d_in[2];
    const float* bias  = (const float*)d_in[3];
    const float* gamma = (const float*)d_in[4];
    const float* beta  = (const float*)d_in[5];
    const void*  sc    = d_in[6];
    const int*   gridc = (const int*)d_in[7];
    float* out = (float*)d_out;
    char* ws = (char*)d_ws;

    int*   inv    = (int*)(ws + WS_INV);
    int*   cnt    = (int*)(ws + WS_CNT);
    int*   base   = (int*)(ws + WS_BASE);
    int*   binbuf = (int*)(ws + WS_BINBUF);
    float* bs     = (float*)(ws + WS_BS);
    float* bsq    = (float*)(ws + WS_BSQ);
    float* mv     = (float*)(ws + WS_MV);
    int*   flag   = (int*)(ws + WS_FLAG);

    hipMemsetAsync(cnt, 0, 2 * K * sizeof(int), stream);
    detect_kernel<<<1, 64, 0, stream>>>((const unsigned int*)sc, flag);
    build_inv_kernel<<<N / 256, 256, 0, stream>>>(sc, flag, inv);
    gemm_max_kernel<<<N / 256, 512, 0, stream>>>(feat, W, bias, inv, out);
    cluster_prep_kernel<<<K / 256, 256, 0, stream>>>(inv, sc, flag, coord, gridc, out, cnt, binbuf);
    scan_kernel<<<2, 1024, 0, stream>>>(cnt, base);
    scatter_kernel<<<(2 * K) / 256, 256, 0, stream>>>(cnt, base, binbuf, out);
    colreduce_kernel<<<256, 256, 0, stream>>>(out, bs, bsq);
    finalize_kernel<<<1, 256, 0, stream>>>(bs, bsq, mv);
    bn_gelu_kernel<<<(K * 256) / (256 * 4), 256, 0, stream>>>(out, mv, gamma, beta);
}